// Round 14
// baseline (262.583 us; speedup 1.0000x reference)
//
#include <hip/hip_runtime.h>

// GraphSAGE 3-layer (mean agg), N=100000, E=1600000, 128->32->32->16.
// Round 14: (a) proj NPT=4/OPT=4 — 16 FMA per single ds_read_b128 (W shared
// across 4 nodes) + W register prefetch; FMA-issue floor is 10.4us, round-13's
// 42us was the 16FMA:2ds serialized form. (b) gather reverted to f32 p
// (round 13 proved gather is latency-bound, not HBM-bound: FETCH 90->27MB but
// dur 40->48us from unpack+reduce overhead). (c) pairs packed to 1 int
// (src | dstlocal<<20) — halves part/build traffic.

#define BLOCK 256
#define NBLK 256            // blocks for hist/part passes
#define BSH 9               // 512 nodes per bucket
#define CAP 12288           // max edges per bucket staged in LDS

// ---------------- phase 1: per-(bucket,block) histogram of dst ----------------
__global__ void hist_kernel(const int* __restrict__ dst, int* __restrict__ hist,
                            int n_edges, int nbuk, int ch) {
    __shared__ int cnt[256];
    int tid = threadIdx.x;
    for (int i = tid; i < nbuk; i += BLOCK) cnt[i] = 0;
    __syncthreads();
    int e0 = blockIdx.x * ch;
    int e1 = e0 + ch; if (e1 > n_edges) e1 = n_edges;
    for (int e = e0 + tid; e < e1; e += BLOCK)
        atomicAdd(&cnt[dst[e] >> BSH], 1);
    __syncthreads();
    for (int i = tid; i < nbuk; i += BLOCK)
        hist[i * NBLK + blockIdx.x] = cnt[i];
}

// ---------------- phase 2a: per-bucket exclusive scan of its 256 block-counts ----------------
__global__ void scanBlk_kernel(int* __restrict__ hist, int* __restrict__ buktot) {
    int b = blockIdx.x;
    int tid = threadIdx.x;
    int orig = hist[b * NBLK + tid];
    int v = orig;
    int lane = tid & 63, w = tid >> 6;
#pragma unroll
    for (int off = 1; off < 64; off <<= 1) {
        int u = __shfl_up(v, off);
        if (lane >= off) v += u;
    }
    __shared__ int wps[4];
    if (lane == 63) wps[w] = v;
    __syncthreads();
    int wadd = 0;
    for (int k = 0; k < w; ++k) wadd += wps[k];
    int excl = v - orig + wadd;
    hist[b * NBLK + tid] = excl;
    if (tid == 255) buktot[b] = excl + orig;
}

// ---------------- phase 2b: exclusive scan of bucket totals (1 block) ----------------
__global__ void scanBuk_kernel(const int* __restrict__ buktot, int* __restrict__ bukoff,
                               int nbuk, int* __restrict__ startp, int n_nodes, int n_edges) {
    int tid = threadIdx.x;
    int orig = (tid < nbuk) ? buktot[tid] : 0;
    int v = orig;
    int lane = tid & 63, w = tid >> 6;
#pragma unroll
    for (int off = 1; off < 64; off <<= 1) {
        int u = __shfl_up(v, off);
        if (lane >= off) v += u;
    }
    __shared__ int wps[4];
    if (lane == 63) wps[w] = v;
    __syncthreads();
    int wadd = 0;
    for (int k = 0; k < w; ++k) wadd += wps[k];
    int excl = v - orig + wadd;
    if (tid < nbuk) bukoff[tid] = excl;
    if (tid == 0) { bukoff[nbuk] = n_edges; startp[n_nodes] = n_edges; }
}

// ---------------- phase 3: partition packed (src|dl<<20) bucket-contiguously ----------------
__global__ void part_kernel(const int* __restrict__ src, const int* __restrict__ dst,
                            const int* __restrict__ hist, const int* __restrict__ bukoff,
                            unsigned* __restrict__ pairs, int n_edges, int nbuk, int ch) {
    __shared__ int base[256];
    __shared__ int cnt[256];
    int tid = threadIdx.x;
    for (int i = tid; i < nbuk; i += BLOCK) {
        base[i] = hist[i * NBLK + blockIdx.x] + bukoff[i];
        cnt[i] = 0;
    }
    __syncthreads();
    int e0 = blockIdx.x * ch;
    int e1 = e0 + ch; if (e1 > n_edges) e1 = n_edges;
    for (int e = e0 + tid; e < e1; e += BLOCK) {
        int d = dst[e];
        int b = d >> BSH;
        unsigned dl = (unsigned)(d & ((1 << BSH) - 1));
        int r = atomicAdd(&cnt[b], 1);
        pairs[base[b] + r] = (unsigned)src[e] | (dl << 20);
    }
}

// ---------------- phase 4: per-bucket CSR build in LDS ----------------
__global__ void build_kernel(const unsigned* __restrict__ pairs, const int* __restrict__ bukoff,
                             int* __restrict__ start, float* __restrict__ invdeg,
                             int* __restrict__ csr_src, int n_nodes) {
    __shared__ int deg[512];
    __shared__ int lst[512];
    __shared__ int cur[512];
    __shared__ int wps[4];
    __shared__ int scsr[CAP];

    int b = blockIdx.x;
    int tid = threadIdx.x;
    int e0 = bukoff[b];
    int e1 = bukoff[b + 1];
    int lo = b << BSH;
    int hi = lo + (1 << BSH); if (hi > n_nodes) hi = n_nodes;
    int nn = hi - lo;
    int ne = e1 - e0;

    for (int i = tid; i < 512; i += BLOCK) deg[i] = 0;
    __syncthreads();
    for (int i = e0 + tid; i < e1; i += BLOCK)
        atomicAdd(&deg[pairs[i] >> 20], 1);
    __syncthreads();

    int d0 = deg[2 * tid], d1 = deg[2 * tid + 1];
    int s = d0 + d1;
    int lane = tid & 63, w = tid >> 6;
    int v = s;
#pragma unroll
    for (int off = 1; off < 64; off <<= 1) {
        int u = __shfl_up(v, off);
        if (lane >= off) v += u;
    }
    if (lane == 63) wps[w] = v;
    __syncthreads();
    int wb = 0;
    for (int k = 0; k < w; ++k) wb += wps[k];
    int excl = wb + v - s;
    lst[2 * tid] = excl;
    lst[2 * tid + 1] = excl + d0;
    cur[2 * tid] = 0;
    cur[2 * tid + 1] = 0;
    __syncthreads();

    for (int i = tid; i < nn; i += BLOCK) {
        start[lo + i] = e0 + lst[i];
        int d = deg[i];
        invdeg[lo + i] = 1.0f / (float)(d < 1 ? 1 : d);
    }

    if (ne <= CAP) {
        for (int i = e0 + tid; i < e1; i += BLOCK) {
            unsigned pr = pairs[i];
            int dl = pr >> 20;
            int sl = lst[dl] + atomicAdd(&cur[dl], 1);
            scsr[sl] = (int)(pr & 0xFFFFFu);
        }
        __syncthreads();
        for (int i = tid; i < ne; i += BLOCK) csr_src[e0 + i] = scsr[i];
    } else {
        for (int i = e0 + tid; i < e1; i += BLOCK) {
            unsigned pr = pairs[i];
            int dl = pr >> 20;
            int sl = lst[dl] + atomicAdd(&cur[dl], 1);
            csr_src[e0 + sl] = (int)(pr & 0xFFFFFu);
        }
    }
}

// ---------------- projection: pre = h@Ws + b ; p = h@Wn ----------------
// NPT=4 nodes x OPT=4 outputs per thread: 16 FMA per SINGLE ds_read_b128
// (W row shared across the 4 nodes), W register-prefetched one k ahead.
// W+bias staged in LDS once; x float4 broadcast from global.
template<int DIN, int DOUT>
__global__ __launch_bounds__(256, 4)
void proj_reg(const float* __restrict__ h,
              const float* __restrict__ Ws,
              const float* __restrict__ Wn,
              const float* __restrict__ bias,
              float* __restrict__ pre,
              float* __restrict__ p,
              int n_nodes) {
    constexpr int OD  = 2 * DOUT;       // 64 or 32
    constexpr int OG  = OD / 4;         // output groups (16 or 8)
    constexpr int NG  = 256 / OG;       // node groups (16 or 32)
    constexpr int NT  = 4 * NG;         // node tile (64 or 128)

    __shared__ float sW[DIN][OD];
    __shared__ float sb[DOUT];

    const int tid = threadIdx.x;
    for (int i = tid; i < DIN * OD; i += 256) {
        int k = i / OD, o = i % OD;
        sW[k][o] = (o < DOUT) ? Ws[k * DOUT + o] : Wn[k * DOUT + (o - DOUT)];
    }
    if (tid < DOUT) sb[tid] = bias[tid];
    __syncthreads();

    const int to = tid % OG;
    const int tn = tid / OG;
    const int o0 = to * 4;
    const int node0 = blockIdx.x * NT + tn * 4;

    const float4* __restrict__ xp[4];
#pragma unroll
    for (int n = 0; n < 4; ++n) {
        int node = node0 + n;
        int safe = (node < n_nodes) ? node : (n_nodes - 1);
        xp[n] = reinterpret_cast<const float4*>(h + (size_t)safe * DIN);
    }

    float acc[4][4];
#pragma unroll
    for (int n = 0; n < 4; ++n)
#pragma unroll
        for (int o = 0; o < 4; ++o) acc[n][o] = 0.f;

    float4 wcur = *reinterpret_cast<const float4*>(&sW[0][o0]);
#pragma unroll 2
    for (int k4 = 0; k4 < DIN / 4; ++k4) {
        float4 xv[4];
#pragma unroll
        for (int n = 0; n < 4; ++n) xv[n] = xp[n][k4];
#pragma unroll
        for (int kk = 0; kk < 4; ++kk) {
            int k = 4 * k4 + kk;
            float4 wnext = (k + 1 < DIN)
                ? *reinterpret_cast<const float4*>(&sW[k + 1][o0]) : wcur;
#pragma unroll
            for (int n = 0; n < 4; ++n) {
                float xk = reinterpret_cast<const float*>(&xv[n])[kk];
                acc[n][0] = fmaf(xk, wcur.x, acc[n][0]);
                acc[n][1] = fmaf(xk, wcur.y, acc[n][1]);
                acc[n][2] = fmaf(xk, wcur.z, acc[n][2]);
                acc[n][3] = fmaf(xk, wcur.w, acc[n][3]);
            }
            wcur = wnext;
        }
    }

    const bool self_half = (o0 < DOUT);
    const int oo = self_half ? o0 : (o0 - DOUT);
    float* __restrict__ dstbuf = self_half ? pre : p;
#pragma unroll
    for (int n = 0; n < 4; ++n) {
        int node = node0 + n;
        if (node >= n_nodes) continue;
        float4 r;
        r.x = acc[n][0]; r.y = acc[n][1]; r.z = acc[n][2]; r.w = acc[n][3];
        if (self_half) {
            r.x += sb[oo + 0]; r.y += sb[oo + 1];
            r.z += sb[oo + 2]; r.w += sb[oo + 3];
        }
        *reinterpret_cast<float4*>(dstbuf + (size_t)node * DOUT + oo) = r;
    }
}

// ---------------- float4 sub-group gather + finalize (f32, round-12 form) ----------------
template<int D, bool RELU>
__global__ void gather_kernel(const float* __restrict__ p,
                              const int* __restrict__ csr_src,
                              const int* __restrict__ start,
                              const float* __restrict__ pre,
                              const float* __restrict__ invdeg,
                              float* __restrict__ out,
                              int n_nodes) {
    constexpr int LPN = D / 4;
    constexpr int NPG = 64 / LPN;
    int wave = threadIdx.x >> 6;
    int lane = threadIdx.x & 63;
    int g = blockIdx.x * (blockDim.x >> 6) + wave;
    if (g >= n_nodes) return;
    int sub = lane / LPN;
    int fl  = lane % LPN;
    int s0 = start[g];
    int s1 = start[g + 1];
    const float4* __restrict__ p4 = reinterpret_cast<const float4*>(p);
    float4 a0 = make_float4(0.f, 0.f, 0.f, 0.f);
    float4 a1 = make_float4(0.f, 0.f, 0.f, 0.f);
    int j = s0 + sub;
    for (; j + NPG < s1; j += 2 * NPG) {
        int c0 = csr_src[j];
        int c1 = csr_src[j + NPG];
        float4 v0 = p4[(size_t)c0 * LPN + fl];
        float4 v1 = p4[(size_t)c1 * LPN + fl];
        a0.x += v0.x; a0.y += v0.y; a0.z += v0.z; a0.w += v0.w;
        a1.x += v1.x; a1.y += v1.y; a1.z += v1.z; a1.w += v1.w;
    }
    if (j < s1) {
        float4 v = p4[(size_t)csr_src[j] * LPN + fl];
        a0.x += v.x; a0.y += v.y; a0.z += v.z; a0.w += v.w;
    }
    float4 a = make_float4(a0.x + a1.x, a0.y + a1.y, a0.z + a1.z, a0.w + a1.w);
#pragma unroll
    for (int off = 32; off >= LPN; off >>= 1) {
        a.x += __shfl_down(a.x, off);
        a.y += __shfl_down(a.y, off);
        a.z += __shfl_down(a.z, off);
        a.w += __shfl_down(a.w, off);
    }
    if (lane < LPN) {
        float id = invdeg[g];
        float4 pr = reinterpret_cast<const float4*>(pre)[(size_t)g * LPN + fl];
        float4 r;
        r.x = pr.x + a.x * id;
        r.y = pr.y + a.y * id;
        r.z = pr.z + a.z * id;
        r.w = pr.w + a.w * id;
        if (RELU) {
            r.x = fmaxf(r.x, 0.f); r.y = fmaxf(r.y, 0.f);
            r.z = fmaxf(r.z, 0.f); r.w = fmaxf(r.w, 0.f);
        }
        reinterpret_cast<float4*>(out)[(size_t)g * LPN + fl] = r;
    }
}

extern "C" void kernel_launch(void* const* d_in, const int* in_sizes, int n_in,
                              void* d_out, int out_size, void* d_ws, size_t ws_size,
                              hipStream_t stream) {
    const float* x        = (const float*)d_in[0];
    const int*   edge_src = (const int*)d_in[1];
    const int*   edge_dst = (const int*)d_in[2];
    const float* Ws1 = (const float*)d_in[3];
    const float* Wn1 = (const float*)d_in[4];
    const float* b1  = (const float*)d_in[5];
    const float* Ws2 = (const float*)d_in[6];
    const float* Wn2 = (const float*)d_in[7];
    const float* b2  = (const float*)d_in[8];
    const float* Ws3 = (const float*)d_in[9];
    const float* Wn3 = (const float*)d_in[10];
    const float* b3  = (const float*)d_in[11];
    float* out = (float*)d_out;

    const int IN = 128, HID = 32;
    const int n_nodes = in_sizes[0] / IN;
    const int n_edges = in_sizes[1];
    const int nbuk = (n_nodes + (1 << BSH) - 1) >> BSH;   // 196
    const int ch   = (n_edges + NBLK - 1) / NBLK;         // 6250

    char* wsb = (char*)d_ws;
    size_t off = 0;
    auto alloc = [&](size_t bytes) { char* r = wsb + off; off = (off + bytes + 255) & ~(size_t)255; return r; };
    int*   startp = (int*)alloc(((size_t)n_nodes + 1) * sizeof(int));
    float* invdeg = (float*)alloc((size_t)n_nodes * sizeof(float));
    int*   csr    = (int*)alloc((size_t)n_edges * sizeof(int));
    int*   hist   = (int*)alloc((size_t)nbuk * NBLK * sizeof(int));
    int*   buktot = (int*)alloc(256 * sizeof(int));
    int*   bukoff = (int*)alloc(257 * sizeof(int));
    float* B0     = (float*)alloc((size_t)n_nodes * HID * sizeof(float));  // pre
    float* B1     = (float*)alloc((size_t)n_nodes * HID * sizeof(float));  // p
    float* B3     = (float*)alloc((size_t)n_nodes * HID * sizeof(float));  // h
    unsigned* pairs = (unsigned*)B0;   // CSR build fully precedes proj1 (6.4MB < B0)

    const int gP12  = (n_nodes + 63) / 64;     // proj layers 1-2: NT=64
    const int gP3   = (n_nodes + 127) / 128;   // proj layer 3:   NT=128
    const int gGat  = (n_nodes + 3) / 4;       // 4 waves/block

    // ---- CSR build: hist -> hierarchical scan -> partition -> per-bucket build ----
    hist_kernel   <<<NBLK, BLOCK, 0, stream>>>(edge_dst, hist, n_edges, nbuk, ch);
    scanBlk_kernel<<<nbuk, BLOCK, 0, stream>>>(hist, buktot);
    scanBuk_kernel<<<1, BLOCK, 0, stream>>>(buktot, bukoff, nbuk, startp, n_nodes, n_edges);
    part_kernel   <<<NBLK, BLOCK, 0, stream>>>(edge_src, edge_dst, hist, bukoff, pairs, n_edges, nbuk, ch);
    build_kernel  <<<nbuk, BLOCK, 0, stream>>>(pairs, bukoff, startp, invdeg, csr, n_nodes);

    // ---- layer 1: 128 -> 32, relu ----
    proj_reg<128, 32><<<gP12, BLOCK, 0, stream>>>(x, Ws1, Wn1, b1, B0, B1, n_nodes);
    gather_kernel<32, true><<<gGat, BLOCK, 0, stream>>>(B1, csr, startp, B0, invdeg, B3, n_nodes);

    // ---- layer 2: 32 -> 32, relu ----
    proj_reg<32, 32><<<gP12, BLOCK, 0, stream>>>(B3, Ws2, Wn2, b2, B0, B1, n_nodes);
    gather_kernel<32, true><<<gGat, BLOCK, 0, stream>>>(B1, csr, startp, B0, invdeg, B3, n_nodes);

    // ---- layer 3: 32 -> 16, no relu ----
    proj_reg<32, 16><<<gP3, BLOCK, 0, stream>>>(B3, Ws3, Wn3, b3, B0, B1, n_nodes);
    gather_kernel<16, false><<<gGat, BLOCK, 0, stream>>>(B1, csr, startp, B0, invdeg, out, n_nodes);
}

// Round 15
// 205.000 us; speedup vs baseline: 1.2809x; 1.2809x over previous
//
#include <hip/hip_runtime.h>

// GraphSAGE 3-layer (mean agg), N=100000, E=1600000, 128->32->32->16.
// Round 15 = round 12 base (best, 217us) + three deltas:
// (a) proj: manual k-unroll-2 -> 4 independent ds_read_b128 in flight per
//     2 k-steps (r14's depth-1 prefetch serialized + its OPT=4 layout had
//     800K bank conflicts; r12's OPT=8/32B-stride layout is conflict-free).
// (b) gather: feature-parallel (lane=feature, 64/D nodes/wave), 8-deep
//     unrolled neighbor loads, NO shuffle reduce.
// (c) pairs packed to 1 int (src | dl<<20) — r14 showed neutral.

#define BLOCK 256
#define NBLK 256            // blocks for hist/part passes
#define BSH 9               // 512 nodes per bucket
#define CAP 12288           // max edges per bucket staged in LDS

// ---------------- phase 1: per-(bucket,block) histogram of dst ----------------
__global__ void hist_kernel(const int* __restrict__ dst, int* __restrict__ hist,
                            int n_edges, int nbuk, int ch) {
    __shared__ int cnt[256];
    int tid = threadIdx.x;
    for (int i = tid; i < nbuk; i += BLOCK) cnt[i] = 0;
    __syncthreads();
    int e0 = blockIdx.x * ch;
    int e1 = e0 + ch; if (e1 > n_edges) e1 = n_edges;
    for (int e = e0 + tid; e < e1; e += BLOCK)
        atomicAdd(&cnt[dst[e] >> BSH], 1);
    __syncthreads();
    for (int i = tid; i < nbuk; i += BLOCK)
        hist[i * NBLK + blockIdx.x] = cnt[i];
}

// ---------------- phase 2a: per-bucket exclusive scan of its 256 block-counts ----------------
__global__ void scanBlk_kernel(int* __restrict__ hist, int* __restrict__ buktot) {
    int b = blockIdx.x;
    int tid = threadIdx.x;
    int orig = hist[b * NBLK + tid];
    int v = orig;
    int lane = tid & 63, w = tid >> 6;
#pragma unroll
    for (int off = 1; off < 64; off <<= 1) {
        int u = __shfl_up(v, off);
        if (lane >= off) v += u;
    }
    __shared__ int wps[4];
    if (lane == 63) wps[w] = v;
    __syncthreads();
    int wadd = 0;
    for (int k = 0; k < w; ++k) wadd += wps[k];
    int excl = v - orig + wadd;
    hist[b * NBLK + tid] = excl;
    if (tid == 255) buktot[b] = excl + orig;
}

// ---------------- phase 2b: exclusive scan of bucket totals (1 block) ----------------
__global__ void scanBuk_kernel(const int* __restrict__ buktot, int* __restrict__ bukoff,
                               int nbuk, int* __restrict__ startp, int n_nodes, int n_edges) {
    int tid = threadIdx.x;
    int orig = (tid < nbuk) ? buktot[tid] : 0;
    int v = orig;
    int lane = tid & 63, w = tid >> 6;
#pragma unroll
    for (int off = 1; off < 64; off <<= 1) {
        int u = __shfl_up(v, off);
        if (lane >= off) v += u;
    }
    __shared__ int wps[4];
    if (lane == 63) wps[w] = v;
    __syncthreads();
    int wadd = 0;
    for (int k = 0; k < w; ++k) wadd += wps[k];
    int excl = v - orig + wadd;
    if (tid < nbuk) bukoff[tid] = excl;
    if (tid == 0) { bukoff[nbuk] = n_edges; startp[n_nodes] = n_edges; }
}

// ---------------- phase 3: partition packed (src|dl<<20) bucket-contiguously ----------------
__global__ void part_kernel(const int* __restrict__ src, const int* __restrict__ dst,
                            const int* __restrict__ hist, const int* __restrict__ bukoff,
                            unsigned* __restrict__ pairs, int n_edges, int nbuk, int ch) {
    __shared__ int base[256];
    __shared__ int cnt[256];
    int tid = threadIdx.x;
    for (int i = tid; i < nbuk; i += BLOCK) {
        base[i] = hist[i * NBLK + blockIdx.x] + bukoff[i];
        cnt[i] = 0;
    }
    __syncthreads();
    int e0 = blockIdx.x * ch;
    int e1 = e0 + ch; if (e1 > n_edges) e1 = n_edges;
    for (int e = e0 + tid; e < e1; e += BLOCK) {
        int d = dst[e];
        int b = d >> BSH;
        unsigned dl = (unsigned)(d & ((1 << BSH) - 1));
        int r = atomicAdd(&cnt[b], 1);
        pairs[base[b] + r] = (unsigned)src[e] | (dl << 20);
    }
}

// ---------------- phase 4: per-bucket CSR build in LDS ----------------
__global__ void build_kernel(const unsigned* __restrict__ pairs, const int* __restrict__ bukoff,
                             int* __restrict__ start, float* __restrict__ invdeg,
                             int* __restrict__ csr_src, int n_nodes) {
    __shared__ int deg[512];
    __shared__ int lst[512];
    __shared__ int cur[512];
    __shared__ int wps[4];
    __shared__ int scsr[CAP];

    int b = blockIdx.x;
    int tid = threadIdx.x;
    int e0 = bukoff[b];
    int e1 = bukoff[b + 1];
    int lo = b << BSH;
    int hi = lo + (1 << BSH); if (hi > n_nodes) hi = n_nodes;
    int nn = hi - lo;
    int ne = e1 - e0;

    for (int i = tid; i < 512; i += BLOCK) deg[i] = 0;
    __syncthreads();
    for (int i = e0 + tid; i < e1; i += BLOCK)
        atomicAdd(&deg[pairs[i] >> 20], 1);
    __syncthreads();

    int d0 = deg[2 * tid], d1 = deg[2 * tid + 1];
    int s = d0 + d1;
    int lane = tid & 63, w = tid >> 6;
    int v = s;
#pragma unroll
    for (int off = 1; off < 64; off <<= 1) {
        int u = __shfl_up(v, off);
        if (lane >= off) v += u;
    }
    if (lane == 63) wps[w] = v;
    __syncthreads();
    int wb = 0;
    for (int k = 0; k < w; ++k) wb += wps[k];
    int excl = wb + v - s;
    lst[2 * tid] = excl;
    lst[2 * tid + 1] = excl + d0;
    cur[2 * tid] = 0;
    cur[2 * tid + 1] = 0;
    __syncthreads();

    for (int i = tid; i < nn; i += BLOCK) {
        start[lo + i] = e0 + lst[i];
        int d = deg[i];
        invdeg[lo + i] = 1.0f / (float)(d < 1 ? 1 : d);
    }

    if (ne <= CAP) {
        for (int i = e0 + tid; i < e1; i += BLOCK) {
            unsigned pr = pairs[i];
            int dl = pr >> 20;
            int sl = lst[dl] + atomicAdd(&cur[dl], 1);
            scsr[sl] = (int)(pr & 0xFFFFFu);
        }
        __syncthreads();
        for (int i = tid; i < ne; i += BLOCK) csr_src[e0 + i] = scsr[i];
    } else {
        for (int i = e0 + tid; i < e1; i += BLOCK) {
            unsigned pr = pairs[i];
            int dl = pr >> 20;
            int sl = lst[dl] + atomicAdd(&cur[dl], 1);
            csr_src[e0 + sl] = (int)(pr & 0xFFFFFu);
        }
    }
}

// ---------------- projection: pre = h@Ws + b ; p = h@Wn ----------------
// W + bias staged in LDS once. x float4 broadcast from global. NPT=2, NT=64.
// Inner loop k-unrolled x2: 2*NV independent ds_read_b128 in flight.
template<int DIN, int DOUT, int OPT, int NPT>
__global__ __launch_bounds__(256, 4)
void proj_reg(const float* __restrict__ h,
              const float* __restrict__ Ws,
              const float* __restrict__ Wn,
              const float* __restrict__ bias,
              float* __restrict__ pre,
              float* __restrict__ p,
              int n_nodes) {
    constexpr int OD  = 2 * DOUT;
    constexpr int OG  = OD / OPT;       // output groups (8)
    constexpr int NG  = 256 / OG;       // node groups
    constexpr int NT  = NPT * NG;       // node tile (64)
    constexpr int NV  = OPT / 4;        // float4s of output per thread

    __shared__ float sW[DIN][OD];
    __shared__ float sb[DOUT];

    const int tid = threadIdx.x;
    for (int i = tid; i < DIN * OD; i += 256) {
        int k = i / OD, o = i % OD;
        sW[k][o] = (o < DOUT) ? Ws[k * DOUT + o] : Wn[k * DOUT + (o - DOUT)];
    }
    if (tid < DOUT) sb[tid] = bias[tid];
    __syncthreads();

    const int to = tid % OG;
    const int tn = tid / OG;
    const int o0 = to * OPT;
    const int node0 = blockIdx.x * NT + tn * NPT;

    const float4* __restrict__ xp[NPT];
#pragma unroll
    for (int n = 0; n < NPT; ++n) {
        int node = node0 + n;
        int safe = (node < n_nodes) ? node : (n_nodes - 1);
        xp[n] = reinterpret_cast<const float4*>(h + (size_t)safe * DIN);
    }

    float acc[NPT][OPT];
#pragma unroll
    for (int n = 0; n < NPT; ++n)
#pragma unroll
        for (int o = 0; o < OPT; ++o) acc[n][o] = 0.f;

#pragma unroll 2
    for (int k4 = 0; k4 < DIN / 4; ++k4) {
        float4 xv[NPT];
#pragma unroll
        for (int n = 0; n < NPT; ++n) xv[n] = xp[n][k4];
#pragma unroll
        for (int kk = 0; kk < 4; kk += 2) {
            int k = 4 * k4 + kk;
            float4 w0[NV], w1[NV];
#pragma unroll
            for (int v = 0; v < NV; ++v) {
                w0[v] = *reinterpret_cast<const float4*>(&sW[k][o0 + 4 * v]);
                w1[v] = *reinterpret_cast<const float4*>(&sW[k + 1][o0 + 4 * v]);
            }
#pragma unroll
            for (int n = 0; n < NPT; ++n) {
                float xk = reinterpret_cast<const float*>(&xv[n])[kk];
#pragma unroll
                for (int v = 0; v < NV; ++v) {
                    acc[n][4 * v + 0] = fmaf(xk, w0[v].x, acc[n][4 * v + 0]);
                    acc[n][4 * v + 1] = fmaf(xk, w0[v].y, acc[n][4 * v + 1]);
                    acc[n][4 * v + 2] = fmaf(xk, w0[v].z, acc[n][4 * v + 2]);
                    acc[n][4 * v + 3] = fmaf(xk, w0[v].w, acc[n][4 * v + 3]);
                }
            }
#pragma unroll
            for (int n = 0; n < NPT; ++n) {
                float xk = reinterpret_cast<const float*>(&xv[n])[kk + 1];
#pragma unroll
                for (int v = 0; v < NV; ++v) {
                    acc[n][4 * v + 0] = fmaf(xk, w1[v].x, acc[n][4 * v + 0]);
                    acc[n][4 * v + 1] = fmaf(xk, w1[v].y, acc[n][4 * v + 1]);
                    acc[n][4 * v + 2] = fmaf(xk, w1[v].z, acc[n][4 * v + 2]);
                    acc[n][4 * v + 3] = fmaf(xk, w1[v].w, acc[n][4 * v + 3]);
                }
            }
        }
    }

    const bool self_half = (o0 < DOUT);
    const int oo = self_half ? o0 : (o0 - DOUT);
    float* __restrict__ dstbuf = self_half ? pre : p;
#pragma unroll
    for (int n = 0; n < NPT; ++n) {
        int node = node0 + n;
        if (node >= n_nodes) continue;
#pragma unroll
        for (int v = 0; v < NV; ++v) {
            float4 r;
            r.x = acc[n][4 * v + 0];
            r.y = acc[n][4 * v + 1];
            r.z = acc[n][4 * v + 2];
            r.w = acc[n][4 * v + 3];
            if (self_half) {
                r.x += sb[oo + 4 * v + 0];
                r.y += sb[oo + 4 * v + 1];
                r.z += sb[oo + 4 * v + 2];
                r.w += sb[oo + 4 * v + 3];
            }
            *reinterpret_cast<float4*>(dstbuf + (size_t)node * DOUT + oo + 4 * v) = r;
        }
    }
}

// ---------------- feature-parallel gather + finalize (no reduce) ----------------
// Lane owns one feature column; 64/D nodes per wave; 8 independent neighbor
// row loads in flight; accumulate in registers; no cross-lane reduction.
template<int D, bool RELU>
__global__ void gather_kernel(const float* __restrict__ p,
                              const int* __restrict__ csr_src,
                              const int* __restrict__ start,
                              const float* __restrict__ pre,
                              const float* __restrict__ invdeg,
                              float* __restrict__ out,
                              int n_nodes) {
    constexpr int NPW = 64 / D;         // nodes per wave (2 or 4)
    int wave = threadIdx.x >> 6;
    int lane = threadIdx.x & 63;
    int g = (blockIdx.x * (blockDim.x >> 6) + wave) * NPW + lane / D;
    int f = lane % D;
    if (g >= n_nodes) return;
    int s0 = start[g];
    int s1 = start[g + 1];
    float a0 = 0.f, a1 = 0.f, a2 = 0.f, a3 = 0.f;
    float a4 = 0.f, a5 = 0.f, a6 = 0.f, a7 = 0.f;
    int j = s0;
    for (; j + 8 <= s1; j += 8) {
        int c0 = csr_src[j + 0], c1 = csr_src[j + 1];
        int c2 = csr_src[j + 2], c3 = csr_src[j + 3];
        int c4 = csr_src[j + 4], c5 = csr_src[j + 5];
        int c6 = csr_src[j + 6], c7 = csr_src[j + 7];
        a0 += p[(size_t)c0 * D + f];
        a1 += p[(size_t)c1 * D + f];
        a2 += p[(size_t)c2 * D + f];
        a3 += p[(size_t)c3 * D + f];
        a4 += p[(size_t)c4 * D + f];
        a5 += p[(size_t)c5 * D + f];
        a6 += p[(size_t)c6 * D + f];
        a7 += p[(size_t)c7 * D + f];
    }
    for (; j + 2 <= s1; j += 2) {
        int c0 = csr_src[j], c1 = csr_src[j + 1];
        a0 += p[(size_t)c0 * D + f];
        a1 += p[(size_t)c1 * D + f];
    }
    if (j < s1) a2 += p[(size_t)csr_src[j] * D + f];
    float a = ((a0 + a1) + (a2 + a3)) + ((a4 + a5) + (a6 + a7));
    size_t o = (size_t)g * D + f;
    float v = pre[o] + a * invdeg[g];
    if (RELU) v = fmaxf(v, 0.f);
    out[o] = v;
}

extern "C" void kernel_launch(void* const* d_in, const int* in_sizes, int n_in,
                              void* d_out, int out_size, void* d_ws, size_t ws_size,
                              hipStream_t stream) {
    const float* x        = (const float*)d_in[0];
    const int*   edge_src = (const int*)d_in[1];
    const int*   edge_dst = (const int*)d_in[2];
    const float* Ws1 = (const float*)d_in[3];
    const float* Wn1 = (const float*)d_in[4];
    const float* b1  = (const float*)d_in[5];
    const float* Ws2 = (const float*)d_in[6];
    const float* Wn2 = (const float*)d_in[7];
    const float* b2  = (const float*)d_in[8];
    const float* Ws3 = (const float*)d_in[9];
    const float* Wn3 = (const float*)d_in[10];
    const float* b3  = (const float*)d_in[11];
    float* out = (float*)d_out;

    const int IN = 128, HID = 32;
    const int n_nodes = in_sizes[0] / IN;
    const int n_edges = in_sizes[1];
    const int nbuk = (n_nodes + (1 << BSH) - 1) >> BSH;   // 196
    const int ch   = (n_edges + NBLK - 1) / NBLK;         // 6250

    char* wsb = (char*)d_ws;
    size_t off = 0;
    auto alloc = [&](size_t bytes) { char* r = wsb + off; off = (off + bytes + 255) & ~(size_t)255; return r; };
    int*   startp = (int*)alloc(((size_t)n_nodes + 1) * sizeof(int));
    float* invdeg = (float*)alloc((size_t)n_nodes * sizeof(float));
    int*   csr    = (int*)alloc((size_t)n_edges * sizeof(int));
    int*   hist   = (int*)alloc((size_t)nbuk * NBLK * sizeof(int));
    int*   buktot = (int*)alloc(256 * sizeof(int));
    int*   bukoff = (int*)alloc(257 * sizeof(int));
    float* B0     = (float*)alloc((size_t)n_nodes * HID * sizeof(float));  // pre
    float* B1     = (float*)alloc((size_t)n_nodes * HID * sizeof(float));  // p
    float* B3     = (float*)alloc((size_t)n_nodes * HID * sizeof(float));  // h
    unsigned* pairs = (unsigned*)B0;   // CSR build fully precedes proj1 (6.4MB < B0)

    const int gP     = (n_nodes + 63) / 64;      // proj NT=64
    const int gGat32 = (n_nodes + 7) / 8;        // 8 nodes/block (2/wave x 4)
    const int gGat16 = (n_nodes + 15) / 16;      // 16 nodes/block

    // ---- CSR build: hist -> hierarchical scan -> partition -> per-bucket build ----
    hist_kernel   <<<NBLK, BLOCK, 0, stream>>>(edge_dst, hist, n_edges, nbuk, ch);
    scanBlk_kernel<<<nbuk, BLOCK, 0, stream>>>(hist, buktot);
    scanBuk_kernel<<<1, BLOCK, 0, stream>>>(buktot, bukoff, nbuk, startp, n_nodes, n_edges);
    part_kernel   <<<NBLK, BLOCK, 0, stream>>>(edge_src, edge_dst, hist, bukoff, pairs, n_edges, nbuk, ch);
    build_kernel  <<<nbuk, BLOCK, 0, stream>>>(pairs, bukoff, startp, invdeg, csr, n_nodes);

    // ---- layer 1: 128 -> 32, relu ----
    proj_reg<128, 32, 8, 2><<<gP, BLOCK, 0, stream>>>(x, Ws1, Wn1, b1, B0, B1, n_nodes);
    gather_kernel<32, true><<<gGat32, BLOCK, 0, stream>>>(B1, csr, startp, B0, invdeg, B3, n_nodes);

    // ---- layer 2: 32 -> 32, relu ----
    proj_reg<32, 32, 8, 2><<<gP, BLOCK, 0, stream>>>(B3, Ws2, Wn2, b2, B0, B1, n_nodes);
    gather_kernel<32, true><<<gGat32, BLOCK, 0, stream>>>(B1, csr, startp, B0, invdeg, B3, n_nodes);

    // ---- layer 3: 32 -> 16, no relu ----
    proj_reg<32, 16, 4, 2><<<gP, BLOCK, 0, stream>>>(B3, Ws3, Wn3, b3, B0, B1, n_nodes);
    gather_kernel<16, false><<<gGat16, BLOCK, 0, stream>>>(B1, csr, startp, B0, invdeg, out, n_nodes);
}